// Round 1
// baseline (473.196 us; speedup 1.0000x reference)
//
#include <hip/hip_runtime.h>
#include <hip/hip_bf16.h>
#include <math.h>

#define NN 4096
#define DD 256

typedef __bf16 bf16x8 __attribute__((ext_vector_type(8)));
typedef short  short8 __attribute__((ext_vector_type(8)));
typedef float  f32x4  __attribute__((ext_vector_type(4)));

#define MFMA16(a, b, c) __builtin_amdgcn_mfma_f32_16x16x32_bf16((a), (b), (c), 0, 0, 0)

__device__ inline bf16x8 brelu(bf16x8 a) {
    short8 s = __builtin_bit_cast(short8, a);
    s = s & ~(s >> 15);            // negative (sign bit set) -> 0, else keep
    return __builtin_bit_cast(bf16x8, s);
}

__device__ inline float wave_red(float v) {
#pragma unroll
    for (int o = 32; o > 0; o >>= 1) v += __shfl_down(v, o, 64);
    return v;
}

// ---------------- prep: cur/pre -> bf16 (+transposed), zero scalars ----------------
__global__ __launch_bounds__(256) void k_prep(const float* __restrict__ cur,
                                              const float* __restrict__ pre,
                                              __bf16* __restrict__ cur_bf,
                                              __bf16* __restrict__ curT,
                                              __bf16* __restrict__ preT,
                                              float* __restrict__ scalars) {
    const int i = blockIdx.x, t = threadIdx.x;
    float c = cur[(size_t)i * DD + t];
    cur_bf[(size_t)i * DD + t] = (__bf16)c;
    curT[(size_t)t * NN + i] = (__bf16)c;
    float p = pre[(size_t)i * DD + t];
    preT[(size_t)t * NN + i] = (__bf16)p;
    if (i == 0 && t < 8) scalars[t] = 0.f;
}

// ---------------- proj matrices -> bf16 transposed ([n][k]); theta_w as-is ----------------
__global__ __launch_bounds__(256) void k_proj(
    const float* __restrict__ a0, const float* __restrict__ a1, const float* __restrict__ a2,
    const float* __restrict__ a3, const float* __restrict__ a4, const float* __restrict__ a5,
    __bf16* __restrict__ o0, __bf16* __restrict__ o1, __bf16* __restrict__ o2,
    __bf16* __restrict__ o3, __bf16* __restrict__ o4, __bf16* __restrict__ o5) {
    const int id = blockIdx.y, r = blockIdx.x, t = threadIdx.x;
    const float* src = id == 0 ? a0 : id == 1 ? a1 : id == 2 ? a2 : id == 3 ? a3 : id == 4 ? a4 : a5;
    __bf16* dst = id == 0 ? o0 : id == 1 ? o1 : id == 2 ? o2 : id == 3 ? o3 : id == 4 ? o4 : o5;
    float v = src[r * DD + t];
    if (id < 5) dst[t * DD + r] = (__bf16)v;   // transposed: T[n][k] = src[k][n]
    else        dst[r * DD + t] = (__bf16)v;   // theta_w stays [j][k] (that IS B^T layout)
}

// ---------------- incidence_t -> bf16, rowsum(relu), sum|x|, sum x^2 ----------------
__global__ __launch_bounds__(256) void k_conv_t(const float* __restrict__ inc,
                                                __bf16* __restrict__ Mbf,
                                                float* __restrict__ rowsum,
                                                float* __restrict__ sabs, float* __restrict__ ssq) {
    const int i = blockIdx.x, t = threadIdx.x;
    const float* src = inc + (size_t)i * NN + t * 16;
    float rs = 0.f, as = 0.f, qs = 0.f;
    __bf16 tmp[16];
#pragma unroll
    for (int e4 = 0; e4 < 4; ++e4) {
        float4 v = ((const float4*)src)[e4];
        float x[4] = {v.x, v.y, v.z, v.w};
#pragma unroll
        for (int j = 0; j < 4; ++j) {
            float f = x[j];
            as += fabsf(f); qs += f * f; rs += fmaxf(f, 0.f);
            tmp[e4 * 4 + j] = (__bf16)f;
        }
    }
    __bf16* dst = Mbf + (size_t)i * NN + t * 16;
    ((uint4*)dst)[0] = *(uint4*)&tmp[0];
    ((uint4*)dst)[1] = *(uint4*)&tmp[8];
    __shared__ float red[3][4];
    const int w = t >> 6, lane = t & 63;
    rs = wave_red(rs); as = wave_red(as); qs = wave_red(qs);
    if (lane == 0) { red[0][w] = rs; red[1][w] = as; red[2][w] = qs; }
    __syncthreads();
    if (t == 0) {
        rowsum[i] = red[0][0] + red[0][1] + red[0][2] + red[0][3];
        atomicAdd(sabs, red[1][0] + red[1][1] + red[1][2] + red[1][3]);
        atomicAdd(ssq,  red[2][0] + red[2][1] + red[2][2] + red[2][3]);
    }
}

// ---------------- incidence_s [N,N-1] -> scattered zero-diag [N,N] bf16 + sums ----------------
__global__ __launch_bounds__(256) void k_conv_s(const float* __restrict__ inc,
                                                __bf16* __restrict__ Mbf,
                                                float* __restrict__ rowsum,
                                                float* __restrict__ sabs, float* __restrict__ ssq) {
    const int i = blockIdx.x, t = threadIdx.x;
    const float* srow = inc + (size_t)i * (NN - 1);
    float rs = 0.f, as = 0.f, qs = 0.f;
    __bf16 tmp[16];
    const int j0 = t * 16;
#pragma unroll
    for (int e = 0; e < 16; ++e) {
        int j = j0 + e;
        float f = 0.f;
        if (j != i) f = srow[j - (j > i ? 1 : 0)];
        as += fabsf(f); qs += f * f; rs += fmaxf(f, 0.f);
        tmp[e] = (__bf16)f;
    }
    __bf16* dst = Mbf + (size_t)i * NN + j0;
    ((uint4*)dst)[0] = *(uint4*)&tmp[0];
    ((uint4*)dst)[1] = *(uint4*)&tmp[8];
    __shared__ float red[3][4];
    const int w = t >> 6, lane = t & 63;
    rs = wave_red(rs); as = wave_red(as); qs = wave_red(qs);
    if (lane == 0) { red[0][w] = rs; red[1][w] = as; red[2][w] = qs; }
    __syncthreads();
    if (t == 0) {
        rowsum[i] = red[0][0] + red[0][1] + red[0][2] + red[0][3];
        atomicAdd(sabs, red[1][0] + red[1][1] + red[1][2] + red[1][3]);
        atomicAdd(ssq,  red[2][0] + red[2][1] + red[2][2] + red[2][3]);
    }
}

// ---------------- shared MFMA inner step (64x64 tile, BK=64, 4 waves in 2x2) ----------------
template <int DUAL>
__device__ inline void mfma_step(const __bf16 (&As)[64][72], const __bf16 (&Bs)[64][72],
                                 int wr, int wc, int quad, int l16,
                                 f32x4 (&accR)[2][2], f32x4 (&accL)[2][2]) {
#pragma unroll
    for (int ks = 0; ks < 2; ++ks) {
        const int kc = ks * 32 + quad * 8;
        bf16x8 a0 = *(const bf16x8*)&As[wr * 32 + l16][kc];
        bf16x8 a1 = *(const bf16x8*)&As[wr * 32 + 16 + l16][kc];
        bf16x8 b0 = *(const bf16x8*)&Bs[wc * 32 + l16][kc];
        bf16x8 b1 = *(const bf16x8*)&Bs[wc * 32 + 16 + l16][kc];
        accR[0][0] = MFMA16(a0, b0, accR[0][0]);
        accR[0][1] = MFMA16(a0, b1, accR[0][1]);
        accR[1][0] = MFMA16(a1, b0, accR[1][0]);
        accR[1][1] = MFMA16(a1, b1, accR[1][1]);
        if (DUAL) {
            bf16x8 a0r = brelu(a0), a1r = brelu(a1);
            accL[0][0] = MFMA16(a0r, b0, accL[0][0]);
            accL[0][1] = MFMA16(a0r, b1, accL[0][1]);
            accL[1][0] = MFMA16(a1r, b0, accL[1][0]);
            accL[1][1] = MFMA16(a1r, b1, accL[1][1]);
        }
    }
}

// ---------------- big dual GEMM: raw (for fro-diff) + relu (for edge features) ----------------
__global__ __launch_bounds__(256) void k_big(const __bf16* __restrict__ Mt, const __bf16* __restrict__ Ms,
                                             const __bf16* __restrict__ preT, const __bf16* __restrict__ curT,
                                             const float* __restrict__ negMt, const float* __restrict__ negMs,
                                             const float* __restrict__ cur,
                                             float* __restrict__ feaT, float* __restrict__ feaS,
                                             float* __restrict__ scalars) {
    const int z = blockIdx.z;
    const __bf16* A  = z ? Ms : Mt;
    const __bf16* BT = z ? curT : preT;
    const float* negM = z ? negMs : negMt;
    float* fea = z ? feaS : feaT;
    float* sd = scalars + (z ? 5 : 4);
    const int n0 = blockIdx.x * 64, m0 = blockIdx.y * 64;
    __shared__ __bf16 As[64][72], Bs[64][72];
    f32x4 accR[2][2], accL[2][2];
#pragma unroll
    for (int i = 0; i < 2; ++i)
#pragma unroll
        for (int j = 0; j < 2; ++j) { accR[i][j] = (f32x4)0.f; accL[i][j] = (f32x4)0.f; }
    const int t = threadIdx.x, w = t >> 6, lane = t & 63, quad = lane >> 4, l16 = lane & 15;
    const int wr = w >> 1, wc = w & 1;
    const int sr = t >> 2, sc = (t & 3) * 16;
    const __bf16* gA = A + (size_t)(m0 + sr) * NN + sc;
    const __bf16* gB = BT + (size_t)(n0 + sr) * NN + sc;
    for (int kt = 0; kt < NN / 64; ++kt) {
        uint4 av0 = *(const uint4*)(gA);
        uint4 av1 = *(const uint4*)(gA + 8);
        uint4 bv0 = *(const uint4*)(gB);
        uint4 bv1 = *(const uint4*)(gB + 8);
        __syncthreads();
        *(uint4*)&As[sr][sc] = av0; *(uint4*)&As[sr][sc + 8] = av1;
        *(uint4*)&Bs[sr][sc] = bv0; *(uint4*)&Bs[sr][sc + 8] = bv1;
        __syncthreads();
        mfma_step<1>(As, Bs, wr, wc, quad, l16, accR, accL);
        gA += 64; gB += 64;
    }
    float sumd = 0.f;
#pragma unroll
    for (int mi = 0; mi < 2; ++mi)
#pragma unroll
        for (int ni = 0; ni < 2; ++ni)
#pragma unroll
            for (int r = 0; r < 4; ++r) {
                int gr = m0 + wr * 32 + mi * 16 + quad * 4 + r;
                int gc = n0 + wc * 32 + ni * 16 + l16;
                size_t idx = (size_t)gr * DD + gc;
                float diff = accR[mi][ni][r] + negM[idx];   // recon - master
                sumd += diff * diff;
                fea[idx] = accL[mi][ni][r] + cur[idx];      // relu-product + cur
            }
    sumd = wave_red(sumd);
    if (lane == 0) atomicAdd(sd, sumd);
}

// ---------------- small GEMMs: -master_s, -master_t, node_fea ----------------
__global__ __launch_bounds__(256) void k_small3(const __bf16* __restrict__ cur_bf,
                                                const __bf16* __restrict__ pTs, const __bf16* __restrict__ pTt,
                                                const __bf16* __restrict__ pTn,
                                                float* __restrict__ negMs, float* __restrict__ negMt,
                                                float* __restrict__ nodeFea) {
    const int z = blockIdx.z;
    const __bf16* BT = z == 0 ? pTs : (z == 1 ? pTt : pTn);
    const int n0 = blockIdx.x * 64, m0 = blockIdx.y * 64;
    __shared__ __bf16 As[64][72], Bs[64][72];
    f32x4 accR[2][2];
#pragma unroll
    for (int i = 0; i < 2; ++i)
#pragma unroll
        for (int j = 0; j < 2; ++j) accR[i][j] = (f32x4)0.f;
    const int t = threadIdx.x, w = t >> 6, lane = t & 63, quad = lane >> 4, l16 = lane & 15;
    const int wr = w >> 1, wc = w & 1;
    const int sr = t >> 2, sc = (t & 3) * 16;
    const __bf16* gA = cur_bf + (size_t)(m0 + sr) * DD + sc;
    const __bf16* gB = BT + (size_t)(n0 + sr) * DD + sc;
    for (int kt = 0; kt < DD / 64; ++kt) {
        uint4 av0 = *(const uint4*)(gA);
        uint4 av1 = *(const uint4*)(gA + 8);
        uint4 bv0 = *(const uint4*)(gB);
        uint4 bv1 = *(const uint4*)(gB + 8);
        __syncthreads();
        *(uint4*)&As[sr][sc] = av0; *(uint4*)&As[sr][sc + 8] = av1;
        *(uint4*)&Bs[sr][sc] = bv0; *(uint4*)&Bs[sr][sc + 8] = bv1;
        __syncthreads();
        mfma_step<0>(As, Bs, wr, wc, quad, l16, accR, accR);
        gA += 64; gB += 64;
    }
#pragma unroll
    for (int mi = 0; mi < 2; ++mi)
#pragma unroll
        for (int ni = 0; ni < 2; ++ni)
#pragma unroll
            for (int r = 0; r < 4; ++r) {
                int gr = m0 + wr * 32 + mi * 16 + quad * 4 + r;
                int gc = n0 + wc * 32 + ni * 16 + l16;
                size_t idx = (size_t)gr * DD + gc;
                float v = accR[mi][ni][r];
                if (z == 0) negMs[idx] = -v;
                else if (z == 1) negMt[idx] = -v;
                else nodeFea[idx] = v;
            }
}

// ---------------- edge-feature projections: spa_fea / tmp_fea (A built on the fly) ----------------
__global__ __launch_bounds__(256) void k_fea(const float* __restrict__ feaS, const float* __restrict__ feaT,
                                             const float* __restrict__ rsS, const float* __restrict__ rsT,
                                             const __bf16* __restrict__ pTspa, const __bf16* __restrict__ pTtmp,
                                             float* __restrict__ spaF, float* __restrict__ tmpF) {
    const int z = blockIdx.z;
    const float* fea = z ? feaT : feaS;
    const float* rs = z ? rsT : rsS;
    const __bf16* BT = z ? pTtmp : pTspa;
    float* outF = z ? tmpF : spaF;
    const int n0 = blockIdx.x * 64, m0 = blockIdx.y * 64;
    __shared__ __bf16 As[64][72], Bs[64][72];
    f32x4 accR[2][2];
#pragma unroll
    for (int i = 0; i < 2; ++i)
#pragma unroll
        for (int j = 0; j < 2; ++j) accR[i][j] = (f32x4)0.f;
    const int t = threadIdx.x, w = t >> 6, lane = t & 63, quad = lane >> 4, l16 = lane & 15;
    const int wr = w >> 1, wc = w & 1;
    const int sr = t >> 2, sc = (t & 3) * 16;
    const float inv = 1.f / (rs[m0 + sr] + 1.f);
    const float* gA = fea + (size_t)(m0 + sr) * DD + sc;
    const __bf16* gB = BT + (size_t)(n0 + sr) * DD + sc;
    for (int kt = 0; kt < DD / 64; ++kt) {
        __bf16 tmp[16];
#pragma unroll
        for (int e4 = 0; e4 < 4; ++e4) {
            float4 v = ((const float4*)gA)[e4];
            tmp[e4 * 4 + 0] = (__bf16)(v.x * inv);
            tmp[e4 * 4 + 1] = (__bf16)(v.y * inv);
            tmp[e4 * 4 + 2] = (__bf16)(v.z * inv);
            tmp[e4 * 4 + 3] = (__bf16)(v.w * inv);
        }
        uint4 bv0 = *(const uint4*)(gB);
        uint4 bv1 = *(const uint4*)(gB + 8);
        __syncthreads();
        *(uint4*)&As[sr][sc] = *(uint4*)&tmp[0]; *(uint4*)&As[sr][sc + 8] = *(uint4*)&tmp[8];
        *(uint4*)&Bs[sr][sc] = bv0; *(uint4*)&Bs[sr][sc + 8] = bv1;
        __syncthreads();
        mfma_step<0>(As, Bs, wr, wc, quad, l16, accR, accR);
        gA += 64; gB += 64;
    }
#pragma unroll
    for (int mi = 0; mi < 2; ++mi)
#pragma unroll
        for (int ni = 0; ni < 2; ++ni)
#pragma unroll
            for (int r = 0; r < 4; ++r) {
                int gr = m0 + wr * 32 + mi * 16 + quad * 4 + r;
                int gc = n0 + wc * 32 + ni * 16 + l16;
                outF[(size_t)gr * DD + gc] = accR[mi][ni][r];
            }
}

// ---------------- attention scalars ----------------
__global__ __launch_bounds__(256) void k_attn(const float* __restrict__ spaF, const float* __restrict__ tmpF,
                                              const float* __restrict__ nodeF,
                                              float* __restrict__ spaA, float* __restrict__ tmpA) {
    const int t = threadIdx.x, w = t >> 6, lane = t & 63;
    const int i = blockIdx.x * 4 + w;
    const float4* sf = (const float4*)(spaF + (size_t)i * DD);
    const float4* tf = (const float4*)(tmpF + (size_t)i * DD);
    const float4* nf = (const float4*)(nodeF + (size_t)i * DD);
    float4 s = sf[lane], p = tf[lane], n = nf[lane];
    float ds = s.x * n.x + s.y * n.y + s.z * n.z + s.w * n.w;
    float dt = p.x * n.x + p.y * n.y + p.z * n.z + p.w * n.w;
    ds = wave_red(ds); dt = wave_red(dt);
    if (lane == 0) { spaA[i] = ds * 0.0625f; tmpA[i] = dt * 0.0625f; }  // 1/sqrt(256)
}

// ---------------- final: val @ theta_w^T + b, relu -> d_out ----------------
__global__ __launch_bounds__(256) void k_final(const float* __restrict__ spaF, const float* __restrict__ tmpF,
                                               const float* __restrict__ spaA, const float* __restrict__ tmpA,
                                               const __bf16* __restrict__ thetaBf, const float* __restrict__ thetaB,
                                               float* __restrict__ out) {
    const int n0 = blockIdx.x * 64, m0 = blockIdx.y * 64;
    __shared__ __bf16 As[64][72], Bs[64][72];
    f32x4 accR[2][2];
#pragma unroll
    for (int i = 0; i < 2; ++i)
#pragma unroll
        for (int j = 0; j < 2; ++j) accR[i][j] = (f32x4)0.f;
    const int t = threadIdx.x, w = t >> 6, lane = t & 63, quad = lane >> 4, l16 = lane & 15;
    const int wr = w >> 1, wc = w & 1;
    const int sr = t >> 2, sc = (t & 3) * 16;
    const float sa = spaA[m0 + sr], ta = tmpA[m0 + sr];
    const float* gS = spaF + (size_t)(m0 + sr) * DD + sc;
    const float* gT = tmpF + (size_t)(m0 + sr) * DD + sc;
    const __bf16* gB = thetaBf + (size_t)(n0 + sr) * DD + sc;
    for (int kt = 0; kt < DD / 64; ++kt) {
        __bf16 tmp[16];
#pragma unroll
        for (int e4 = 0; e4 < 4; ++e4) {
            float4 vs = ((const float4*)gS)[e4];
            float4 vt = ((const float4*)gT)[e4];
            tmp[e4 * 4 + 0] = (__bf16)(sa * vs.x + ta * vt.x);
            tmp[e4 * 4 + 1] = (__bf16)(sa * vs.y + ta * vt.y);
            tmp[e4 * 4 + 2] = (__bf16)(sa * vs.z + ta * vt.z);
            tmp[e4 * 4 + 3] = (__bf16)(sa * vs.w + ta * vt.w);
        }
        uint4 bv0 = *(const uint4*)(gB);
        uint4 bv1 = *(const uint4*)(gB + 8);
        __syncthreads();
        *(uint4*)&As[sr][sc] = *(uint4*)&tmp[0]; *(uint4*)&As[sr][sc + 8] = *(uint4*)&tmp[8];
        *(uint4*)&Bs[sr][sc] = bv0; *(uint4*)&Bs[sr][sc + 8] = bv1;
        __syncthreads();
        mfma_step<0>(As, Bs, wr, wc, quad, l16, accR, accR);
        gS += 64; gT += 64; gB += 64;
    }
#pragma unroll
    for (int mi = 0; mi < 2; ++mi)
#pragma unroll
        for (int ni = 0; ni < 2; ++ni)
#pragma unroll
            for (int r = 0; r < 4; ++r) {
                int gr = m0 + wr * 32 + mi * 16 + quad * 4 + r;
                int gc = n0 + wc * 32 + ni * 16 + l16;
                float v = accR[mi][ni][r] + thetaB[gc];
                out[(size_t)gr * DD + gc] = fmaxf(v, 0.f);
            }
}

// ---------------- loss scalar ----------------
__global__ void k_loss(const float* __restrict__ scalars, float* __restrict__ out) {
    if (threadIdx.x == 0) {
        float l = scalars[0] + 0.001f * sqrtf(scalars[1]) + 0.2f * sqrtf(scalars[4])   // temporal
                + scalars[2] + 0.001f * sqrtf(scalars[3]) + 0.2f * sqrtf(scalars[5]);  // spatial
        out[(size_t)NN * DD] = l;
    }
}

extern "C" void kernel_launch(void* const* d_in, const int* in_sizes, int n_in,
                              void* d_out, int out_size, void* d_ws, size_t ws_size,
                              hipStream_t stream) {
    (void)in_sizes; (void)n_in; (void)out_size; (void)ws_size;
    const float* cur      = (const float*)d_in[0];
    const float* pre      = (const float*)d_in[1];
    const float* r_proj_s = (const float*)d_in[2];
    const float* inc_s    = (const float*)d_in[3];
    const float* r_proj_t = (const float*)d_in[4];
    const float* inc_t    = (const float*)d_in[5];
    const float* node_pj  = (const float*)d_in[6];
    const float* spa_pj   = (const float*)d_in[7];
    const float* tmp_pj   = (const float*)d_in[8];
    const float* theta_w  = (const float*)d_in[9];
    const float* theta_b  = (const float*)d_in[10];
    float* out = (float*)d_out;

    char* p = (char*)d_ws;
    auto alloc = [&](size_t bytes) -> void* {
        void* r = (void*)p;
        p += (bytes + 255) & ~(size_t)255;
        return r;
    };
    __bf16* Mt      = (__bf16*)alloc((size_t)NN * NN * 2);
    __bf16* Ms      = (__bf16*)alloc((size_t)NN * NN * 2);
    __bf16* cur_bf  = (__bf16*)alloc((size_t)NN * DD * 2);
    __bf16* curT    = (__bf16*)alloc((size_t)NN * DD * 2);
    __bf16* preT    = (__bf16*)alloc((size_t)NN * DD * 2);
    __bf16* pTs     = (__bf16*)alloc((size_t)DD * DD * 2);
    __bf16* pTt     = (__bf16*)alloc((size_t)DD * DD * 2);
    __bf16* pTn     = (__bf16*)alloc((size_t)DD * DD * 2);
    __bf16* pTspa   = (__bf16*)alloc((size_t)DD * DD * 2);
    __bf16* pTtmp   = (__bf16*)alloc((size_t)DD * DD * 2);
    __bf16* thetaBf = (__bf16*)alloc((size_t)DD * DD * 2);
    float* negMs    = (float*)alloc((size_t)NN * DD * 4);
    float* negMt    = (float*)alloc((size_t)NN * DD * 4);
    float* nodeFea  = (float*)alloc((size_t)NN * DD * 4);
    float* feaS     = (float*)alloc((size_t)NN * DD * 4);
    float* feaT     = (float*)alloc((size_t)NN * DD * 4);
    float* spaF     = (float*)alloc((size_t)NN * DD * 4);
    float* tmpF     = (float*)alloc((size_t)NN * DD * 4);
    float* rsS      = (float*)alloc((size_t)NN * 4);
    float* rsT      = (float*)alloc((size_t)NN * 4);
    float* spaA     = (float*)alloc((size_t)NN * 4);
    float* tmpA     = (float*)alloc((size_t)NN * 4);
    float* scalars  = (float*)alloc(32);
    // scalars: [0]=abs_t [1]=sq_t [2]=abs_s [3]=sq_s [4]=diffsq_t [5]=diffsq_s

    k_prep<<<NN, 256, 0, stream>>>(cur, pre, cur_bf, curT, preT, scalars);
    k_proj<<<dim3(DD, 6), 256, 0, stream>>>(r_proj_s, r_proj_t, node_pj, spa_pj, tmp_pj, theta_w,
                                            pTs, pTt, pTn, pTspa, pTtmp, thetaBf);
    k_conv_t<<<NN, 256, 0, stream>>>(inc_t, Mt, rsT, &scalars[0], &scalars[1]);
    k_conv_s<<<NN, 256, 0, stream>>>(inc_s, Ms, rsS, &scalars[2], &scalars[3]);
    k_small3<<<dim3(4, 64, 3), 256, 0, stream>>>(cur_bf, pTs, pTt, pTn, negMs, negMt, nodeFea);
    k_big<<<dim3(4, 64, 2), 256, 0, stream>>>(Mt, Ms, preT, curT, negMt, negMs, cur, feaT, feaS, scalars);
    k_fea<<<dim3(4, 64, 2), 256, 0, stream>>>(feaS, feaT, rsS, rsT, pTspa, pTtmp, spaF, tmpF);
    k_attn<<<NN / 4, 256, 0, stream>>>(spaF, tmpF, nodeFea, spaA, tmpA);
    k_final<<<dim3(4, 64), 256, 0, stream>>>(spaF, tmpF, spaA, tmpA, thetaBf, theta_b, out);
    k_loss<<<1, 64, 0, stream>>>(scalars, out);
}

// Round 2
// 460.435 us; speedup vs baseline: 1.0277x; 1.0277x over previous
//
#include <hip/hip_runtime.h>
#include <hip/hip_bf16.h>
#include <math.h>

#define NN 4096
#define DD 256

typedef __bf16 bf16x8 __attribute__((ext_vector_type(8)));
typedef short  short8 __attribute__((ext_vector_type(8)));
typedef float  f32x4  __attribute__((ext_vector_type(4)));

#define MFMA16(a, b, c) __builtin_amdgcn_mfma_f32_16x16x32_bf16((a), (b), (c), 0, 0, 0)

__device__ inline bf16x8 brelu(bf16x8 a) {
    short8 s = __builtin_bit_cast(short8, a);
    s = s & ~(s >> 15);            // negative (sign bit set) -> 0, else keep
    return __builtin_bit_cast(bf16x8, s);
}

__device__ inline float wave_red(float v) {
#pragma unroll
    for (int o = 32; o > 0; o >>= 1) v += __shfl_down(v, o, 64);
    return v;
}

__device__ inline unsigned short bfbits(float f) {
    return __builtin_bit_cast(unsigned short, (__bf16)f);
}

// ---------------- prep: 64x64 LDS-tiled transpose; cur/pre -> bf16 (+T), zero scalars ----------------
__global__ __launch_bounds__(256) void k_prep(const float* __restrict__ cur,
                                              const float* __restrict__ pre,
                                              __bf16* __restrict__ cur_bf,
                                              __bf16* __restrict__ curT,
                                              __bf16* __restrict__ preT,
                                              float* __restrict__ scalars) {
    const int z = blockIdx.z;
    const int i0 = blockIdx.x * 64, d0 = blockIdx.y * 64;
    const float* src = z ? pre : cur;
    __bf16* dstT = z ? preT : curT;
    __shared__ unsigned short tile[64][72];
    const int t = threadIdx.x;
    const int r = t >> 2, c4 = (t & 3) * 16;
    const float* srow = src + (size_t)(i0 + r) * DD + d0 + c4;
    alignas(16) unsigned short loc[16];
#pragma unroll
    for (int e = 0; e < 4; ++e) {
        float4 v = ((const float4*)srow)[e];
        loc[e * 4 + 0] = bfbits(v.x);
        loc[e * 4 + 1] = bfbits(v.y);
        loc[e * 4 + 2] = bfbits(v.z);
        loc[e * 4 + 3] = bfbits(v.w);
    }
#pragma unroll
    for (int e = 0; e < 16; ++e) tile[r][c4 + e] = loc[e];
    if (z == 0) {
        __bf16* drow = cur_bf + (size_t)(i0 + r) * DD + d0 + c4;
        *(uint4*)drow = *(uint4*)&loc[0];
        *(uint4*)(drow + 8) = *(uint4*)&loc[8];
    }
    __syncthreads();
    alignas(16) unsigned short o[16];
#pragma unroll
    for (int e = 0; e < 16; ++e) o[e] = tile[c4 + e][r];
    __bf16* trow = dstT + (size_t)(d0 + r) * NN + i0 + c4;
    *(uint4*)trow = *(uint4*)&o[0];
    *(uint4*)(trow + 8) = *(uint4*)&o[8];
    if (z == 0 && blockIdx.x == 0 && blockIdx.y == 0 && t < 8) scalars[t] = 0.f;
}

// ---------------- proj matrices -> bf16 transposed ([n][k]); theta_w as-is ----------------
__global__ __launch_bounds__(256) void k_proj(
    const float* __restrict__ a0, const float* __restrict__ a1, const float* __restrict__ a2,
    const float* __restrict__ a3, const float* __restrict__ a4, const float* __restrict__ a5,
    __bf16* __restrict__ o0, __bf16* __restrict__ o1, __bf16* __restrict__ o2,
    __bf16* __restrict__ o3, __bf16* __restrict__ o4, __bf16* __restrict__ o5) {
    const int id = blockIdx.y, r = blockIdx.x, t = threadIdx.x;
    const float* src = id == 0 ? a0 : id == 1 ? a1 : id == 2 ? a2 : id == 3 ? a3 : id == 4 ? a4 : a5;
    __bf16* dst = id == 0 ? o0 : id == 1 ? o1 : id == 2 ? o2 : id == 3 ? o3 : id == 4 ? o4 : o5;
    float v = src[r * DD + t];
    if (id < 5) dst[t * DD + r] = (__bf16)v;   // transposed: T[n][k] = src[k][n]
    else        dst[r * DD + t] = (__bf16)v;   // theta_w stays [j][k] (that IS B^T layout)
}

// ---------------- incidence_t -> bf16, rowsum(relu), sum|x|, sum x^2 (coalesced) ----------------
__global__ __launch_bounds__(256) void k_conv_t(const float* __restrict__ inc,
                                                __bf16* __restrict__ Mbf,
                                                float* __restrict__ rowsum,
                                                float* __restrict__ sabs, float* __restrict__ ssq) {
    const int i = blockIdx.x, t = threadIdx.x;
    const float4* src = (const float4*)(inc + (size_t)i * NN);
    ushort4* dst = (ushort4*)(Mbf + (size_t)i * NN);
    float rs = 0.f, as = 0.f, qs = 0.f;
#pragma unroll
    for (int e = 0; e < 4; ++e) {
        const int f = t + 256 * e;
        float4 v = src[f];
        float x[4] = {v.x, v.y, v.z, v.w};
        unsigned short o[4];
#pragma unroll
        for (int j = 0; j < 4; ++j) {
            float fv = x[j];
            as += fabsf(fv); qs += fv * fv; rs += fmaxf(fv, 0.f);
            o[j] = bfbits(fv);
        }
        dst[f] = make_ushort4(o[0], o[1], o[2], o[3]);
    }
    __shared__ float red[3][4];
    const int w = t >> 6, lane = t & 63;
    rs = wave_red(rs); as = wave_red(as); qs = wave_red(qs);
    if (lane == 0) { red[0][w] = rs; red[1][w] = as; red[2][w] = qs; }
    __syncthreads();
    if (t == 0) {
        rowsum[i] = red[0][0] + red[0][1] + red[0][2] + red[0][3];
        atomicAdd(sabs, red[1][0] + red[1][1] + red[1][2] + red[1][3]);
        atomicAdd(ssq,  red[2][0] + red[2][1] + red[2][2] + red[2][3]);
    }
}

// ---------------- incidence_s [N,N-1] -> zero-diag [N,N] bf16 via LDS scatter + sums ----------------
__global__ __launch_bounds__(256) void k_conv_s(const float* __restrict__ inc,
                                                __bf16* __restrict__ Mbf,
                                                float* __restrict__ rowsum,
                                                float* __restrict__ sabs, float* __restrict__ ssq) {
    const int i = blockIdx.x, t = threadIdx.x;
    __shared__ unsigned short row[NN];     // 8 KB staging for the scattered output row
    const float* srow = inc + (size_t)i * (NN - 1);
    float rs = 0.f, as = 0.f, qs = 0.f;
#pragma unroll
    for (int e = 0; e < 4; ++e) {
        const int f = t + 256 * e;         // float4-group index within row, [0,1024)
        float x[4] = {0.f, 0.f, 0.f, 0.f};
        if (f < 1023) __builtin_memcpy(x, srow + 4 * f, 16);   // row base only 4B-aligned
        else          __builtin_memcpy(x, srow + 4092, 12);    // tail: 3 valid floats
#pragma unroll
        for (int j = 0; j < 4; ++j) {
            const int k = 4 * f + j;
            float fv = x[j];
            as += fabsf(fv); qs += fv * fv; rs += fmaxf(fv, 0.f);
            if (k < NN - 1) row[k + (k >= i)] = bfbits(fv);
        }
    }
    if (t == 0) row[i] = 0;                // diagonal
    __syncthreads();
    uint4* dOut = (uint4*)(Mbf + (size_t)i * NN);
    const uint4* sIn = (const uint4*)row;
    dOut[t] = sIn[t];
    dOut[t + 256] = sIn[t + 256];
    __shared__ float red[3][4];
    const int w = t >> 6, lane = t & 63;
    rs = wave_red(rs); as = wave_red(as); qs = wave_red(qs);
    if (lane == 0) { red[0][w] = rs; red[1][w] = as; red[2][w] = qs; }
    __syncthreads();
    if (t == 0) {
        rowsum[i] = red[0][0] + red[0][1] + red[0][2] + red[0][3];
        atomicAdd(sabs, red[1][0] + red[1][1] + red[1][2] + red[1][3]);
        atomicAdd(ssq,  red[2][0] + red[2][1] + red[2][2] + red[2][3]);
    }
}

// ---------------- shared MFMA inner step (64x64 tile, BK=64, 4 waves in 2x2) ----------------
template <int DUAL>
__device__ inline void mfma_step(const __bf16 (&As)[64][72], const __bf16 (&Bs)[64][72],
                                 int wr, int wc, int quad, int l16,
                                 f32x4 (&accR)[2][2], f32x4 (&accL)[2][2]) {
#pragma unroll
    for (int ks = 0; ks < 2; ++ks) {
        const int kc = ks * 32 + quad * 8;
        bf16x8 a0 = *(const bf16x8*)&As[wr * 32 + l16][kc];
        bf16x8 a1 = *(const bf16x8*)&As[wr * 32 + 16 + l16][kc];
        bf16x8 b0 = *(const bf16x8*)&Bs[wc * 32 + l16][kc];
        bf16x8 b1 = *(const bf16x8*)&Bs[wc * 32 + 16 + l16][kc];
        accR[0][0] = MFMA16(a0, b0, accR[0][0]);
        accR[0][1] = MFMA16(a0, b1, accR[0][1]);
        accR[1][0] = MFMA16(a1, b0, accR[1][0]);
        accR[1][1] = MFMA16(a1, b1, accR[1][1]);
        if (DUAL) {
            bf16x8 a0r = brelu(a0), a1r = brelu(a1);
            accL[0][0] = MFMA16(a0r, b0, accL[0][0]);
            accL[0][1] = MFMA16(a0r, b1, accL[0][1]);
            accL[1][0] = MFMA16(a1r, b0, accL[1][0]);
            accL[1][1] = MFMA16(a1r, b1, accL[1][1]);
        }
    }
}

// ---------------- big dual GEMM: raw (for fro-diff) + relu (for edge features) ----------------
__global__ __launch_bounds__(256) void k_big(const __bf16* __restrict__ Mt, const __bf16* __restrict__ Ms,
                                             const __bf16* __restrict__ preT, const __bf16* __restrict__ curT,
                                             const float* __restrict__ negMt, const float* __restrict__ negMs,
                                             const float* __restrict__ cur,
                                             float* __restrict__ feaT, float* __restrict__ feaS,
                                             float* __restrict__ scalars) {
    const int z = blockIdx.z;
    const __bf16* A  = z ? Ms : Mt;
    const __bf16* BT = z ? curT : preT;
    const float* negM = z ? negMs : negMt;
    float* fea = z ? feaS : feaT;
    float* sd = scalars + (z ? 5 : 4);
    const int n0 = blockIdx.x * 64, m0 = blockIdx.y * 64;
    __shared__ __bf16 As[64][72], Bs[64][72];
    f32x4 accR[2][2], accL[2][2];
#pragma unroll
    for (int i = 0; i < 2; ++i)
#pragma unroll
        for (int j = 0; j < 2; ++j) { accR[i][j] = (f32x4)0.f; accL[i][j] = (f32x4)0.f; }
    const int t = threadIdx.x, w = t >> 6, lane = t & 63, quad = lane >> 4, l16 = lane & 15;
    const int wr = w >> 1, wc = w & 1;
    const int sr = t >> 2, sc = (t & 3) * 16;
    const __bf16* gA = A + (size_t)(m0 + sr) * NN + sc;
    const __bf16* gB = BT + (size_t)(n0 + sr) * NN + sc;
    for (int kt = 0; kt < NN / 64; ++kt) {
        uint4 av0 = *(const uint4*)(gA);
        uint4 av1 = *(const uint4*)(gA + 8);
        uint4 bv0 = *(const uint4*)(gB);
        uint4 bv1 = *(const uint4*)(gB + 8);
        __syncthreads();
        *(uint4*)&As[sr][sc] = av0; *(uint4*)&As[sr][sc + 8] = av1;
        *(uint4*)&Bs[sr][sc] = bv0; *(uint4*)&Bs[sr][sc + 8] = bv1;
        __syncthreads();
        mfma_step<1>(As, Bs, wr, wc, quad, l16, accR, accL);
        gA += 64; gB += 64;
    }
    float sumd = 0.f;
#pragma unroll
    for (int mi = 0; mi < 2; ++mi)
#pragma unroll
        for (int ni = 0; ni < 2; ++ni)
#pragma unroll
            for (int r = 0; r < 4; ++r) {
                int gr = m0 + wr * 32 + mi * 16 + quad * 4 + r;
                int gc = n0 + wc * 32 + ni * 16 + l16;
                size_t idx = (size_t)gr * DD + gc;
                float diff = accR[mi][ni][r] + negM[idx];   // recon - master
                sumd += diff * diff;
                fea[idx] = accL[mi][ni][r] + cur[idx];      // relu-product + cur
            }
    sumd = wave_red(sumd);
    if (lane == 0) atomicAdd(sd, sumd);
}

// ---------------- small GEMMs: -master_s, -master_t, node_fea ----------------
__global__ __launch_bounds__(256) void k_small3(const __bf16* __restrict__ cur_bf,
                                                const __bf16* __restrict__ pTs, const __bf16* __restrict__ pTt,
                                                const __bf16* __restrict__ pTn,
                                                float* __restrict__ negMs, float* __restrict__ negMt,
                                                float* __restrict__ nodeFea) {
    const int z = blockIdx.z;
    const __bf16* BT = z == 0 ? pTs : (z == 1 ? pTt : pTn);
    const int n0 = blockIdx.x * 64, m0 = blockIdx.y * 64;
    __shared__ __bf16 As[64][72], Bs[64][72];
    f32x4 accR[2][2];
#pragma unroll
    for (int i = 0; i < 2; ++i)
#pragma unroll
        for (int j = 0; j < 2; ++j) accR[i][j] = (f32x4)0.f;
    const int t = threadIdx.x, w = t >> 6, lane = t & 63, quad = lane >> 4, l16 = lane & 15;
    const int wr = w >> 1, wc = w & 1;
    const int sr = t >> 2, sc = (t & 3) * 16;
    const __bf16* gA = cur_bf + (size_t)(m0 + sr) * DD + sc;
    const __bf16* gB = BT + (size_t)(n0 + sr) * DD + sc;
    for (int kt = 0; kt < DD / 64; ++kt) {
        uint4 av0 = *(const uint4*)(gA);
        uint4 av1 = *(const uint4*)(gA + 8);
        uint4 bv0 = *(const uint4*)(gB);
        uint4 bv1 = *(const uint4*)(gB + 8);
        __syncthreads();
        *(uint4*)&As[sr][sc] = av0; *(uint4*)&As[sr][sc + 8] = av1;
        *(uint4*)&Bs[sr][sc] = bv0; *(uint4*)&Bs[sr][sc + 8] = bv1;
        __syncthreads();
        mfma_step<0>(As, Bs, wr, wc, quad, l16, accR, accR);
        gA += 64; gB += 64;
    }
#pragma unroll
    for (int mi = 0; mi < 2; ++mi)
#pragma unroll
        for (int ni = 0; ni < 2; ++ni)
#pragma unroll
            for (int r = 0; r < 4; ++r) {
                int gr = m0 + wr * 32 + mi * 16 + quad * 4 + r;
                int gc = n0 + wc * 32 + ni * 16 + l16;
                size_t idx = (size_t)gr * DD + gc;
                float v = accR[mi][ni][r];
                if (z == 0) negMs[idx] = -v;
                else if (z == 1) negMt[idx] = -v;
                else nodeFea[idx] = v;
            }
}

// ---------------- edge-feature projections: spa_fea / tmp_fea (A built on the fly) ----------------
__global__ __launch_bounds__(256) void k_fea(const float* __restrict__ feaS, const float* __restrict__ feaT,
                                             const float* __restrict__ rsS, const float* __restrict__ rsT,
                                             const __bf16* __restrict__ pTspa, const __bf16* __restrict__ pTtmp,
                                             float* __restrict__ spaF, float* __restrict__ tmpF) {
    const int z = blockIdx.z;
    const float* fea = z ? feaT : feaS;
    const float* rs = z ? rsT : rsS;
    const __bf16* BT = z ? pTtmp : pTspa;
    float* outF = z ? tmpF : spaF;
    const int n0 = blockIdx.x * 64, m0 = blockIdx.y * 64;
    __shared__ __bf16 As[64][72], Bs[64][72];
    f32x4 accR[2][2];
#pragma unroll
    for (int i = 0; i < 2; ++i)
#pragma unroll
        for (int j = 0; j < 2; ++j) accR[i][j] = (f32x4)0.f;
    const int t = threadIdx.x, w = t >> 6, lane = t & 63, quad = lane >> 4, l16 = lane & 15;
    const int wr = w >> 1, wc = w & 1;
    const int sr = t >> 2, sc = (t & 3) * 16;
    const float inv = 1.f / (rs[m0 + sr] + 1.f);
    const float* gA = fea + (size_t)(m0 + sr) * DD + sc;
    const __bf16* gB = BT + (size_t)(n0 + sr) * DD + sc;
    for (int kt = 0; kt < DD / 64; ++kt) {
        __bf16 tmp[16];
#pragma unroll
        for (int e4 = 0; e4 < 4; ++e4) {
            float4 v = ((const float4*)gA)[e4];
            tmp[e4 * 4 + 0] = (__bf16)(v.x * inv);
            tmp[e4 * 4 + 1] = (__bf16)(v.y * inv);
            tmp[e4 * 4 + 2] = (__bf16)(v.z * inv);
            tmp[e4 * 4 + 3] = (__bf16)(v.w * inv);
        }
        uint4 bv0 = *(const uint4*)(gB);
        uint4 bv1 = *(const uint4*)(gB + 8);
        __syncthreads();
        *(uint4*)&As[sr][sc] = *(uint4*)&tmp[0]; *(uint4*)&As[sr][sc + 8] = *(uint4*)&tmp[8];
        *(uint4*)&Bs[sr][sc] = bv0; *(uint4*)&Bs[sr][sc + 8] = bv1;
        __syncthreads();
        mfma_step<0>(As, Bs, wr, wc, quad, l16, accR, accR);
        gA += 64; gB += 64;
    }
#pragma unroll
    for (int mi = 0; mi < 2; ++mi)
#pragma unroll
        for (int ni = 0; ni < 2; ++ni)
#pragma unroll
            for (int r = 0; r < 4; ++r) {
                int gr = m0 + wr * 32 + mi * 16 + quad * 4 + r;
                int gc = n0 + wc * 32 + ni * 16 + l16;
                outF[(size_t)gr * DD + gc] = accR[mi][ni][r];
            }
}

// ---------------- attention scalars ----------------
__global__ __launch_bounds__(256) void k_attn(const float* __restrict__ spaF, const float* __restrict__ tmpF,
                                              const float* __restrict__ nodeF,
                                              float* __restrict__ spaA, float* __restrict__ tmpA) {
    const int t = threadIdx.x, w = t >> 6, lane = t & 63;
    const int i = blockIdx.x * 4 + w;
    const float4* sf = (const float4*)(spaF + (size_t)i * DD);
    const float4* tf = (const float4*)(tmpF + (size_t)i * DD);
    const float4* nf = (const float4*)(nodeF + (size_t)i * DD);
    float4 s = sf[lane], p = tf[lane], n = nf[lane];
    float ds = s.x * n.x + s.y * n.y + s.z * n.z + s.w * n.w;
    float dt = p.x * n.x + p.y * n.y + p.z * n.z + p.w * n.w;
    ds = wave_red(ds); dt = wave_red(dt);
    if (lane == 0) { spaA[i] = ds * 0.0625f; tmpA[i] = dt * 0.0625f; }  // 1/sqrt(256)
}

// ---------------- final: val @ theta_w^T + b, relu -> d_out ----------------
__global__ __launch_bounds__(256) void k_final(const float* __restrict__ spaF, const float* __restrict__ tmpF,
                                               const float* __restrict__ spaA, const float* __restrict__ tmpA,
                                               const __bf16* __restrict__ thetaBf, const float* __restrict__ thetaB,
                                               float* __restrict__ out) {
    const int n0 = blockIdx.x * 64, m0 = blockIdx.y * 64;
    __shared__ __bf16 As[64][72], Bs[64][72];
    f32x4 accR[2][2];
#pragma unroll
    for (int i = 0; i < 2; ++i)
#pragma unroll
        for (int j = 0; j < 2; ++j) accR[i][j] = (f32x4)0.f;
    const int t = threadIdx.x, w = t >> 6, lane = t & 63, quad = lane >> 4, l16 = lane & 15;
    const int wr = w >> 1, wc = w & 1;
    const int sr = t >> 2, sc = (t & 3) * 16;
    const float sa = spaA[m0 + sr], ta = tmpA[m0 + sr];
    const float* gS = spaF + (size_t)(m0 + sr) * DD + sc;
    const float* gT = tmpF + (size_t)(m0 + sr) * DD + sc;
    const __bf16* gB = thetaBf + (size_t)(n0 + sr) * DD + sc;
    for (int kt = 0; kt < DD / 64; ++kt) {
        __bf16 tmp[16];
#pragma unroll
        for (int e4 = 0; e4 < 4; ++e4) {
            float4 vs = ((const float4*)gS)[e4];
            float4 vt = ((const float4*)gT)[e4];
            tmp[e4 * 4 + 0] = (__bf16)(sa * vs.x + ta * vt.x);
            tmp[e4 * 4 + 1] = (__bf16)(sa * vs.y + ta * vt.y);
            tmp[e4 * 4 + 2] = (__bf16)(sa * vs.z + ta * vt.z);
            tmp[e4 * 4 + 3] = (__bf16)(sa * vs.w + ta * vt.w);
        }
        uint4 bv0 = *(const uint4*)(gB);
        uint4 bv1 = *(const uint4*)(gB + 8);
        __syncthreads();
        *(uint4*)&As[sr][sc] = *(uint4*)&tmp[0]; *(uint4*)&As[sr][sc + 8] = *(uint4*)&tmp[8];
        *(uint4*)&Bs[sr][sc] = bv0; *(uint4*)&Bs[sr][sc + 8] = bv1;
        __syncthreads();
        mfma_step<0>(As, Bs, wr, wc, quad, l16, accR, accR);
        gS += 64; gT += 64; gB += 64;
    }
#pragma unroll
    for (int mi = 0; mi < 2; ++mi)
#pragma unroll
        for (int ni = 0; ni < 2; ++ni)
#pragma unroll
            for (int r = 0; r < 4; ++r) {
                int gr = m0 + wr * 32 + mi * 16 + quad * 4 + r;
                int gc = n0 + wc * 32 + ni * 16 + l16;
                float v = accR[mi][ni][r] + thetaB[gc];
                out[(size_t)gr * DD + gc] = fmaxf(v, 0.f);
            }
}

// ---------------- loss scalar ----------------
__global__ void k_loss(const float* __restrict__ scalars, float* __restrict__ out) {
    if (threadIdx.x == 0) {
        float l = scalars[0] + 0.001f * sqrtf(scalars[1]) + 0.2f * sqrtf(scalars[4])   // temporal
                + scalars[2] + 0.001f * sqrtf(scalars[3]) + 0.2f * sqrtf(scalars[5]);  // spatial
        out[(size_t)NN * DD] = l;
    }
}

extern "C" void kernel_launch(void* const* d_in, const int* in_sizes, int n_in,
                              void* d_out, int out_size, void* d_ws, size_t ws_size,
                              hipStream_t stream) {
    (void)in_sizes; (void)n_in; (void)out_size; (void)ws_size;
    const float* cur      = (const float*)d_in[0];
    const float* pre      = (const float*)d_in[1];
    const float* r_proj_s = (const float*)d_in[2];
    const float* inc_s    = (const float*)d_in[3];
    const float* r_proj_t = (const float*)d_in[4];
    const float* inc_t    = (const float*)d_in[5];
    const float* node_pj  = (const float*)d_in[6];
    const float* spa_pj   = (const float*)d_in[7];
    const float* tmp_pj   = (const float*)d_in[8];
    const float* theta_w  = (const float*)d_in[9];
    const float* theta_b  = (const float*)d_in[10];
    float* out = (float*)d_out;

    char* p = (char*)d_ws;
    auto alloc = [&](size_t bytes) -> void* {
        void* r = (void*)p;
        p += (bytes + 255) & ~(size_t)255;
        return r;
    };
    __bf16* Mt      = (__bf16*)alloc((size_t)NN * NN * 2);
    __bf16* Ms      = (__bf16*)alloc((size_t)NN * NN * 2);
    __bf16* cur_bf  = (__bf16*)alloc((size_t)NN * DD * 2);
    __bf16* curT    = (__bf16*)alloc((size_t)NN * DD * 2);
    __bf16* preT    = (__bf16*)alloc((size_t)NN * DD * 2);
    __bf16* pTs     = (__bf16*)alloc((size_t)DD * DD * 2);
    __bf16* pTt     = (__bf16*)alloc((size_t)DD * DD * 2);
    __bf16* pTn     = (__bf16*)alloc((size_t)DD * DD * 2);
    __bf16* pTspa   = (__bf16*)alloc((size_t)DD * DD * 2);
    __bf16* pTtmp   = (__bf16*)alloc((size_t)DD * DD * 2);
    __bf16* thetaBf = (__bf16*)alloc((size_t)DD * DD * 2);
    float* negMs    = (float*)alloc((size_t)NN * DD * 4);
    float* negMt    = (float*)alloc((size_t)NN * DD * 4);
    float* nodeFea  = (float*)alloc((size_t)NN * DD * 4);
    float* feaS     = (float*)alloc((size_t)NN * DD * 4);
    float* feaT     = (float*)alloc((size_t)NN * DD * 4);
    float* spaF     = (float*)alloc((size_t)NN * DD * 4);
    float* tmpF     = (float*)alloc((size_t)NN * DD * 4);
    float* rsS      = (float*)alloc((size_t)NN * 4);
    float* rsT      = (float*)alloc((size_t)NN * 4);
    float* spaA     = (float*)alloc((size_t)NN * 4);
    float* tmpA     = (float*)alloc((size_t)NN * 4);
    float* scalars  = (float*)alloc(32);
    // scalars: [0]=abs_t [1]=sq_t [2]=abs_s [3]=sq_s [4]=diffsq_t [5]=diffsq_s

    k_prep<<<dim3(NN / 64, DD / 64, 2), 256, 0, stream>>>(cur, pre, cur_bf, curT, preT, scalars);
    k_proj<<<dim3(DD, 6), 256, 0, stream>>>(r_proj_s, r_proj_t, node_pj, spa_pj, tmp_pj, theta_w,
                                            pTs, pTt, pTn, pTspa, pTtmp, thetaBf);
    k_conv_t<<<NN, 256, 0, stream>>>(inc_t, Mt, rsT, &scalars[0], &scalars[1]);
    k_conv_s<<<NN, 256, 0, stream>>>(inc_s, Ms, rsS, &scalars[2], &scalars[3]);
    k_small3<<<dim3(4, 64, 3), 256, 0, stream>>>(cur_bf, pTs, pTt, pTn, negMs, negMt, nodeFea);
    k_big<<<dim3(4, 64, 2), 256, 0, stream>>>(Mt, Ms, preT, curT, negMt, negMs, cur, feaT, feaS, scalars);
    k_fea<<<dim3(4, 64, 2), 256, 0, stream>>>(feaS, feaT, rsS, rsT, pTspa, pTtmp, spaF, tmpF);
    k_attn<<<NN / 4, 256, 0, stream>>>(spaF, tmpF, nodeFea, spaA, tmpA);
    k_final<<<dim3(4, 64), 256, 0, stream>>>(spaF, tmpF, spaA, tmpA, thetaBf, theta_b, out);
    k_loss<<<1, 64, 0, stream>>>(scalars, out);
}

// Round 3
// 268.822 us; speedup vs baseline: 1.7603x; 1.7128x over previous
//
#include <hip/hip_runtime.h>
#include <hip/hip_bf16.h>
#include <math.h>

#define NN 4096
#define DD 256

typedef __bf16 bf16x8 __attribute__((ext_vector_type(8)));
typedef short  short8 __attribute__((ext_vector_type(8)));
typedef float  f32x4  __attribute__((ext_vector_type(4)));

#define MFMA16(a, b, c) __builtin_amdgcn_mfma_f32_16x16x32_bf16((a), (b), (c), 0, 0, 0)

__device__ inline bf16x8 brelu(bf16x8 a) {
    short8 s = __builtin_bit_cast(short8, a);
    s = s & ~(s >> 15);            // negative (sign bit set) -> 0, else keep
    return __builtin_bit_cast(bf16x8, s);
}

__device__ inline float wave_red(float v) {
#pragma unroll
    for (int o = 32; o > 0; o >>= 1) v += __shfl_down(v, o, 64);
    return v;
}

__device__ inline unsigned short bfbits(float f) {
    return __builtin_bit_cast(unsigned short, (__bf16)f);
}

// ---------------- prep: 64x64 LDS-tiled transpose; cur/pre -> bf16 (+T) ----------------
__global__ __launch_bounds__(256) void k_prep(const float* __restrict__ cur,
                                              const float* __restrict__ pre,
                                              __bf16* __restrict__ cur_bf,
                                              __bf16* __restrict__ curT,
                                              __bf16* __restrict__ preT) {
    const int z = blockIdx.z;
    const int i0 = blockIdx.x * 64, d0 = blockIdx.y * 64;
    const float* src = z ? pre : cur;
    __bf16* dstT = z ? preT : curT;
    __shared__ unsigned short tile[64][72];
    const int t = threadIdx.x;
    const int r = t >> 2, c4 = (t & 3) * 16;
    const float* srow = src + (size_t)(i0 + r) * DD + d0 + c4;
    alignas(16) unsigned short loc[16];
#pragma unroll
    for (int e = 0; e < 4; ++e) {
        float4 v = ((const float4*)srow)[e];
        loc[e * 4 + 0] = bfbits(v.x);
        loc[e * 4 + 1] = bfbits(v.y);
        loc[e * 4 + 2] = bfbits(v.z);
        loc[e * 4 + 3] = bfbits(v.w);
    }
#pragma unroll
    for (int e = 0; e < 16; ++e) tile[r][c4 + e] = loc[e];
    if (z == 0) {
        __bf16* drow = cur_bf + (size_t)(i0 + r) * DD + d0 + c4;
        *(uint4*)drow = *(uint4*)&loc[0];
        *(uint4*)(drow + 8) = *(uint4*)&loc[8];
    }
    __syncthreads();
    alignas(16) unsigned short o[16];
#pragma unroll
    for (int e = 0; e < 16; ++e) o[e] = tile[c4 + e][r];
    __bf16* trow = dstT + (size_t)(d0 + r) * NN + i0 + c4;
    *(uint4*)trow = *(uint4*)&o[0];
    *(uint4*)(trow + 8) = *(uint4*)&o[8];
}

// ---------------- proj matrices -> bf16 transposed ([n][k]); theta_w as-is ----------------
__global__ __launch_bounds__(256) void k_proj(
    const float* __restrict__ a0, const float* __restrict__ a1, const float* __restrict__ a2,
    const float* __restrict__ a3, const float* __restrict__ a4, const float* __restrict__ a5,
    __bf16* __restrict__ o0, __bf16* __restrict__ o1, __bf16* __restrict__ o2,
    __bf16* __restrict__ o3, __bf16* __restrict__ o4, __bf16* __restrict__ o5) {
    const int id = blockIdx.y, r = blockIdx.x, t = threadIdx.x;
    const float* src = id == 0 ? a0 : id == 1 ? a1 : id == 2 ? a2 : id == 3 ? a3 : id == 4 ? a4 : a5;
    __bf16* dst = id == 0 ? o0 : id == 1 ? o1 : id == 2 ? o2 : id == 3 ? o3 : id == 4 ? o4 : o5;
    float v = src[r * DD + t];
    if (id < 5) dst[t * DD + r] = (__bf16)v;   // transposed: T[n][k] = src[k][n]
    else        dst[r * DD + t] = (__bf16)v;   // theta_w stays [j][k] (that IS B^T layout)
}

// ---------------- incidence_t -> bf16, rowsum(relu), per-block |x| and x^2 partials ----------------
__global__ __launch_bounds__(256) void k_conv_t(const float* __restrict__ inc,
                                                __bf16* __restrict__ Mbf,
                                                float* __restrict__ rowsum,
                                                float* __restrict__ pAbs, float* __restrict__ pSq) {
    const int i = blockIdx.x, t = threadIdx.x;
    const float4* src = (const float4*)(inc + (size_t)i * NN);
    ushort4* dst = (ushort4*)(Mbf + (size_t)i * NN);
    float rs = 0.f, as = 0.f, qs = 0.f;
#pragma unroll
    for (int e = 0; e < 4; ++e) {
        const int f = t + 256 * e;
        float4 v = src[f];
        float x[4] = {v.x, v.y, v.z, v.w};
        unsigned short o[4];
#pragma unroll
        for (int j = 0; j < 4; ++j) {
            float fv = x[j];
            as += fabsf(fv); qs += fv * fv; rs += fmaxf(fv, 0.f);
            o[j] = bfbits(fv);
        }
        dst[f] = make_ushort4(o[0], o[1], o[2], o[3]);
    }
    __shared__ float red[3][4];
    const int w = t >> 6, lane = t & 63;
    rs = wave_red(rs); as = wave_red(as); qs = wave_red(qs);
    if (lane == 0) { red[0][w] = rs; red[1][w] = as; red[2][w] = qs; }
    __syncthreads();
    if (t == 0) {
        rowsum[i] = red[0][0] + red[0][1] + red[0][2] + red[0][3];
        pAbs[i]   = red[1][0] + red[1][1] + red[1][2] + red[1][3];
        pSq[i]    = red[2][0] + red[2][1] + red[2][2] + red[2][3];
    }
}

// ---------------- incidence_s [N,N-1] -> zero-diag [N,N] bf16 via LDS scatter + partials ----------------
__global__ __launch_bounds__(256) void k_conv_s(const float* __restrict__ inc,
                                                __bf16* __restrict__ Mbf,
                                                float* __restrict__ rowsum,
                                                float* __restrict__ pAbs, float* __restrict__ pSq) {
    const int i = blockIdx.x, t = threadIdx.x;
    __shared__ unsigned short row[NN];     // 8 KB staging for the scattered output row
    const float* srow = inc + (size_t)i * (NN - 1);
    float rs = 0.f, as = 0.f, qs = 0.f;
#pragma unroll
    for (int e = 0; e < 4; ++e) {
        const int f = t + 256 * e;         // float4-group index within row, [0,1024)
        float x[4] = {0.f, 0.f, 0.f, 0.f};
        if (f < 1023) __builtin_memcpy(x, srow + 4 * f, 16);   // row base only 4B-aligned
        else          __builtin_memcpy(x, srow + 4092, 12);    // tail: 3 valid floats
#pragma unroll
        for (int j = 0; j < 4; ++j) {
            const int k = 4 * f + j;
            float fv = x[j];
            as += fabsf(fv); qs += fv * fv; rs += fmaxf(fv, 0.f);
            if (k < NN - 1) row[k + (k >= i)] = bfbits(fv);
        }
    }
    if (t == 0) row[i] = 0;                // diagonal
    __syncthreads();
    uint4* dOut = (uint4*)(Mbf + (size_t)i * NN);
    const uint4* sIn = (const uint4*)row;
    dOut[t] = sIn[t];
    dOut[t + 256] = sIn[t + 256];
    __shared__ float red[3][4];
    const int w = t >> 6, lane = t & 63;
    rs = wave_red(rs); as = wave_red(as); qs = wave_red(qs);
    if (lane == 0) { red[0][w] = rs; red[1][w] = as; red[2][w] = qs; }
    __syncthreads();
    if (t == 0) {
        rowsum[i] = red[0][0] + red[0][1] + red[0][2] + red[0][3];
        pAbs[i]   = red[1][0] + red[1][1] + red[1][2] + red[1][3];
        pSq[i]    = red[2][0] + red[2][1] + red[2][2] + red[2][3];
    }
}

// ---------------- shared MFMA inner step (64x64 tile, BK=64, 4 waves in 2x2) ----------------
template <int DUAL>
__device__ inline void mfma_step(const __bf16 (&As)[64][72], const __bf16 (&Bs)[64][72],
                                 int wr, int wc, int quad, int l16,
                                 f32x4 (&accR)[2][2], f32x4 (&accL)[2][2]) {
#pragma unroll
    for (int ks = 0; ks < 2; ++ks) {
        const int kc = ks * 32 + quad * 8;
        bf16x8 a0 = *(const bf16x8*)&As[wr * 32 + l16][kc];
        bf16x8 a1 = *(const bf16x8*)&As[wr * 32 + 16 + l16][kc];
        bf16x8 b0 = *(const bf16x8*)&Bs[wc * 32 + l16][kc];
        bf16x8 b1 = *(const bf16x8*)&Bs[wc * 32 + 16 + l16][kc];
        accR[0][0] = MFMA16(a0, b0, accR[0][0]);
        accR[0][1] = MFMA16(a0, b1, accR[0][1]);
        accR[1][0] = MFMA16(a1, b0, accR[1][0]);
        accR[1][1] = MFMA16(a1, b1, accR[1][1]);
        if (DUAL) {
            bf16x8 a0r = brelu(a0), a1r = brelu(a1);
            accL[0][0] = MFMA16(a0r, b0, accL[0][0]);
            accL[0][1] = MFMA16(a0r, b1, accL[0][1]);
            accL[1][0] = MFMA16(a1r, b0, accL[1][0]);
            accL[1][1] = MFMA16(a1r, b1, accL[1][1]);
        }
    }
}

// ---------------- big dual GEMM: raw (for fro-diff) + relu (for edge features) ----------------
__global__ __launch_bounds__(256) void k_big(const __bf16* __restrict__ Mt, const __bf16* __restrict__ Ms,
                                             const __bf16* __restrict__ preT, const __bf16* __restrict__ curT,
                                             const float* __restrict__ negMt, const float* __restrict__ negMs,
                                             const float* __restrict__ cur,
                                             float* __restrict__ feaT, float* __restrict__ feaS,
                                             float* __restrict__ pDiff) {
    const int z = blockIdx.z;
    const __bf16* A  = z ? Ms : Mt;
    const __bf16* BT = z ? curT : preT;
    const float* negM = z ? negMs : negMt;
    float* fea = z ? feaS : feaT;
    const int n0 = blockIdx.x * 64, m0 = blockIdx.y * 64;
    __shared__ __bf16 As[64][72], Bs[64][72];
    __shared__ float sred[4];
    f32x4 accR[2][2], accL[2][2];
#pragma unroll
    for (int i = 0; i < 2; ++i)
#pragma unroll
        for (int j = 0; j < 2; ++j) { accR[i][j] = (f32x4)0.f; accL[i][j] = (f32x4)0.f; }
    const int t = threadIdx.x, w = t >> 6, lane = t & 63, quad = lane >> 4, l16 = lane & 15;
    const int wr = w >> 1, wc = w & 1;
    const int sr = t >> 2, sc = (t & 3) * 16;
    const __bf16* gA = A + (size_t)(m0 + sr) * NN + sc;
    const __bf16* gB = BT + (size_t)(n0 + sr) * NN + sc;
    for (int kt = 0; kt < NN / 64; ++kt) {
        uint4 av0 = *(const uint4*)(gA);
        uint4 av1 = *(const uint4*)(gA + 8);
        uint4 bv0 = *(const uint4*)(gB);
        uint4 bv1 = *(const uint4*)(gB + 8);
        __syncthreads();
        *(uint4*)&As[sr][sc] = av0; *(uint4*)&As[sr][sc + 8] = av1;
        *(uint4*)&Bs[sr][sc] = bv0; *(uint4*)&Bs[sr][sc + 8] = bv1;
        __syncthreads();
        mfma_step<1>(As, Bs, wr, wc, quad, l16, accR, accL);
        gA += 64; gB += 64;
    }
    float sumd = 0.f;
#pragma unroll
    for (int mi = 0; mi < 2; ++mi)
#pragma unroll
        for (int ni = 0; ni < 2; ++ni)
#pragma unroll
            for (int r = 0; r < 4; ++r) {
                int gr = m0 + wr * 32 + mi * 16 + quad * 4 + r;
                int gc = n0 + wc * 32 + ni * 16 + l16;
                size_t idx = (size_t)gr * DD + gc;
                float diff = accR[mi][ni][r] + negM[idx];   // recon - master
                sumd += diff * diff;
                fea[idx] = accL[mi][ni][r] + cur[idx];      // relu-product + cur
            }
    sumd = wave_red(sumd);
    if (lane == 0) sred[w] = sumd;
    __syncthreads();
    if (t == 0)
        pDiff[z * 256 + blockIdx.y * 4 + blockIdx.x] = sred[0] + sred[1] + sred[2] + sred[3];
}

// ---------------- small GEMMs: -master_s, -master_t, node_fea ----------------
__global__ __launch_bounds__(256) void k_small3(const __bf16* __restrict__ cur_bf,
                                                const __bf16* __restrict__ pTs, const __bf16* __restrict__ pTt,
                                                const __bf16* __restrict__ pTn,
                                                float* __restrict__ negMs, float* __restrict__ negMt,
                                                float* __restrict__ nodeFea) {
    const int z = blockIdx.z;
    const __bf16* BT = z == 0 ? pTs : (z == 1 ? pTt : pTn);
    const int n0 = blockIdx.x * 64, m0 = blockIdx.y * 64;
    __shared__ __bf16 As[64][72], Bs[64][72];
    f32x4 accR[2][2];
#pragma unroll
    for (int i = 0; i < 2; ++i)
#pragma unroll
        for (int j = 0; j < 2; ++j) accR[i][j] = (f32x4)0.f;
    const int t = threadIdx.x, w = t >> 6, lane = t & 63, quad = lane >> 4, l16 = lane & 15;
    const int wr = w >> 1, wc = w & 1;
    const int sr = t >> 2, sc = (t & 3) * 16;
    const __bf16* gA = cur_bf + (size_t)(m0 + sr) * DD + sc;
    const __bf16* gB = BT + (size_t)(n0 + sr) * DD + sc;
    for (int kt = 0; kt < DD / 64; ++kt) {
        uint4 av0 = *(const uint4*)(gA);
        uint4 av1 = *(const uint4*)(gA + 8);
        uint4 bv0 = *(const uint4*)(gB);
        uint4 bv1 = *(const uint4*)(gB + 8);
        __syncthreads();
        *(uint4*)&As[sr][sc] = av0; *(uint4*)&As[sr][sc + 8] = av1;
        *(uint4*)&Bs[sr][sc] = bv0; *(uint4*)&Bs[sr][sc + 8] = bv1;
        __syncthreads();
        mfma_step<0>(As, Bs, wr, wc, quad, l16, accR, accR);
        gA += 64; gB += 64;
    }
#pragma unroll
    for (int mi = 0; mi < 2; ++mi)
#pragma unroll
        for (int ni = 0; ni < 2; ++ni)
#pragma unroll
            for (int r = 0; r < 4; ++r) {
                int gr = m0 + wr * 32 + mi * 16 + quad * 4 + r;
                int gc = n0 + wc * 32 + ni * 16 + l16;
                size_t idx = (size_t)gr * DD + gc;
                float v = accR[mi][ni][r];
                if (z == 0) negMs[idx] = -v;
                else if (z == 1) negMt[idx] = -v;
                else nodeFea[idx] = v;
            }
}

// ---------------- edge-feature projections: spa_fea / tmp_fea (A built on the fly) ----------------
__global__ __launch_bounds__(256) void k_fea(const float* __restrict__ feaS, const float* __restrict__ feaT,
                                             const float* __restrict__ rsS, const float* __restrict__ rsT,
                                             const __bf16* __restrict__ pTspa, const __bf16* __restrict__ pTtmp,
                                             float* __restrict__ spaF, float* __restrict__ tmpF) {
    const int z = blockIdx.z;
    const float* fea = z ? feaT : feaS;
    const float* rs = z ? rsT : rsS;
    const __bf16* BT = z ? pTtmp : pTspa;
    float* outF = z ? tmpF : spaF;
    const int n0 = blockIdx.x * 64, m0 = blockIdx.y * 64;
    __shared__ __bf16 As[64][72], Bs[64][72];
    f32x4 accR[2][2];
#pragma unroll
    for (int i = 0; i < 2; ++i)
#pragma unroll
        for (int j = 0; j < 2; ++j) accR[i][j] = (f32x4)0.f;
    const int t = threadIdx.x, w = t >> 6, lane = t & 63, quad = lane >> 4, l16 = lane & 15;
    const int wr = w >> 1, wc = w & 1;
    const int sr = t >> 2, sc = (t & 3) * 16;
    const float inv = 1.f / (rs[m0 + sr] + 1.f);
    const float* gA = fea + (size_t)(m0 + sr) * DD + sc;
    const __bf16* gB = BT + (size_t)(n0 + sr) * DD + sc;
    for (int kt = 0; kt < DD / 64; ++kt) {
        __bf16 tmp[16];
#pragma unroll
        for (int e4 = 0; e4 < 4; ++e4) {
            float4 v = ((const float4*)gA)[e4];
            tmp[e4 * 4 + 0] = (__bf16)(v.x * inv);
            tmp[e4 * 4 + 1] = (__bf16)(v.y * inv);
            tmp[e4 * 4 + 2] = (__bf16)(v.z * inv);
            tmp[e4 * 4 + 3] = (__bf16)(v.w * inv);
        }
        uint4 bv0 = *(const uint4*)(gB);
        uint4 bv1 = *(const uint4*)(gB + 8);
        __syncthreads();
        *(uint4*)&As[sr][sc] = *(uint4*)&tmp[0]; *(uint4*)&As[sr][sc + 8] = *(uint4*)&tmp[8];
        *(uint4*)&Bs[sr][sc] = bv0; *(uint4*)&Bs[sr][sc + 8] = bv1;
        __syncthreads();
        mfma_step<0>(As, Bs, wr, wc, quad, l16, accR, accR);
        gA += 64; gB += 64;
    }
#pragma unroll
    for (int mi = 0; mi < 2; ++mi)
#pragma unroll
        for (int ni = 0; ni < 2; ++ni)
#pragma unroll
            for (int r = 0; r < 4; ++r) {
                int gr = m0 + wr * 32 + mi * 16 + quad * 4 + r;
                int gc = n0 + wc * 32 + ni * 16 + l16;
                outF[(size_t)gr * DD + gc] = accR[mi][ni][r];
            }
}

// ---------------- attention scalars ----------------
__global__ __launch_bounds__(256) void k_attn(const float* __restrict__ spaF, const float* __restrict__ tmpF,
                                              const float* __restrict__ nodeF,
                                              float* __restrict__ spaA, float* __restrict__ tmpA) {
    const int t = threadIdx.x, w = t >> 6, lane = t & 63;
    const int i = blockIdx.x * 4 + w;
    const float4* sf = (const float4*)(spaF + (size_t)i * DD);
    const float4* tf = (const float4*)(tmpF + (size_t)i * DD);
    const float4* nf = (const float4*)(nodeF + (size_t)i * DD);
    float4 s = sf[lane], p = tf[lane], n = nf[lane];
    float ds = s.x * n.x + s.y * n.y + s.z * n.z + s.w * n.w;
    float dt = p.x * n.x + p.y * n.y + p.z * n.z + p.w * n.w;
    ds = wave_red(ds); dt = wave_red(dt);
    if (lane == 0) { spaA[i] = ds * 0.0625f; tmpA[i] = dt * 0.0625f; }  // 1/sqrt(256)
}

// ---------------- final: val @ theta_w^T + b, relu -> d_out ----------------
__global__ __launch_bounds__(256) void k_final(const float* __restrict__ spaF, const float* __restrict__ tmpF,
                                               const float* __restrict__ spaA, const float* __restrict__ tmpA,
                                               const __bf16* __restrict__ thetaBf, const float* __restrict__ thetaB,
                                               float* __restrict__ out) {
    const int n0 = blockIdx.x * 64, m0 = blockIdx.y * 64;
    __shared__ __bf16 As[64][72], Bs[64][72];
    f32x4 accR[2][2];
#pragma unroll
    for (int i = 0; i < 2; ++i)
#pragma unroll
        for (int j = 0; j < 2; ++j) accR[i][j] = (f32x4)0.f;
    const int t = threadIdx.x, w = t >> 6, lane = t & 63, quad = lane >> 4, l16 = lane & 15;
    const int wr = w >> 1, wc = w & 1;
    const int sr = t >> 2, sc = (t & 3) * 16;
    const float sa = spaA[m0 + sr], ta = tmpA[m0 + sr];
    const float* gS = spaF + (size_t)(m0 + sr) * DD + sc;
    const float* gT = tmpF + (size_t)(m0 + sr) * DD + sc;
    const __bf16* gB = thetaBf + (size_t)(n0 + sr) * DD + sc;
    for (int kt = 0; kt < DD / 64; ++kt) {
        __bf16 tmp[16];
#pragma unroll
        for (int e4 = 0; e4 < 4; ++e4) {
            float4 vs = ((const float4*)gS)[e4];
            float4 vt = ((const float4*)gT)[e4];
            tmp[e4 * 4 + 0] = (__bf16)(sa * vs.x + ta * vt.x);
            tmp[e4 * 4 + 1] = (__bf16)(sa * vs.y + ta * vt.y);
            tmp[e4 * 4 + 2] = (__bf16)(sa * vs.z + ta * vt.z);
            tmp[e4 * 4 + 3] = (__bf16)(sa * vs.w + ta * vt.w);
        }
        uint4 bv0 = *(const uint4*)(gB);
        uint4 bv1 = *(const uint4*)(gB + 8);
        __syncthreads();
        *(uint4*)&As[sr][sc] = *(uint4*)&tmp[0]; *(uint4*)&As[sr][sc + 8] = *(uint4*)&tmp[8];
        *(uint4*)&Bs[sr][sc] = bv0; *(uint4*)&Bs[sr][sc + 8] = bv1;
        __syncthreads();
        mfma_step<0>(As, Bs, wr, wc, quad, l16, accR, accR);
        gS += 64; gT += 64; gB += 64;
    }
#pragma unroll
    for (int mi = 0; mi < 2; ++mi)
#pragma unroll
        for (int ni = 0; ni < 2; ++ni)
#pragma unroll
            for (int r = 0; r < 4; ++r) {
                int gr = m0 + wr * 32 + mi * 16 + quad * 4 + r;
                int gc = n0 + wc * 32 + ni * 16 + l16;
                float v = accR[mi][ni][r] + thetaB[gc];
                out[(size_t)gr * DD + gc] = fmaxf(v, 0.f);
            }
}

// ---------------- loss: reduce per-block partials, single block ----------------
__global__ __launch_bounds__(256) void k_loss(const float* __restrict__ pAbsT, const float* __restrict__ pSqT,
                                              const float* __restrict__ pAbsS, const float* __restrict__ pSqS,
                                              const float* __restrict__ pDiff,
                                              float* __restrict__ out) {
    const int t = threadIdx.x;
    float aT = 0.f, qT = 0.f, aS = 0.f, qS = 0.f;
#pragma unroll
    for (int j = 0; j < 16; ++j) {
        const int i = t + 256 * j;
        aT += pAbsT[i]; qT += pSqT[i]; aS += pAbsS[i]; qS += pSqS[i];
    }
    float dT = pDiff[t], dS = pDiff[256 + t];
    aT = wave_red(aT); qT = wave_red(qT); aS = wave_red(aS); qS = wave_red(qS);
    dT = wave_red(dT); dS = wave_red(dS);
    __shared__ float red[6][4];
    const int w = t >> 6, lane = t & 63;
    if (lane == 0) { red[0][w] = aT; red[1][w] = qT; red[2][w] = aS; red[3][w] = qS; red[4][w] = dT; red[5][w] = dS; }
    __syncthreads();
    if (t == 0) {
        float s[6];
#pragma unroll
        for (int k = 0; k < 6; ++k) s[k] = red[k][0] + red[k][1] + red[k][2] + red[k][3];
        float l = s[0] + 0.001f * sqrtf(s[1]) + 0.2f * sqrtf(s[4])    // temporal
                + s[2] + 0.001f * sqrtf(s[3]) + 0.2f * sqrtf(s[5]);   // spatial
        out[(size_t)NN * DD] = l;
    }
}

extern "C" void kernel_launch(void* const* d_in, const int* in_sizes, int n_in,
                              void* d_out, int out_size, void* d_ws, size_t ws_size,
                              hipStream_t stream) {
    (void)in_sizes; (void)n_in; (void)out_size; (void)ws_size;
    const float* cur      = (const float*)d_in[0];
    const float* pre      = (const float*)d_in[1];
    const float* r_proj_s = (const float*)d_in[2];
    const float* inc_s    = (const float*)d_in[3];
    const float* r_proj_t = (const float*)d_in[4];
    const float* inc_t    = (const float*)d_in[5];
    const float* node_pj  = (const float*)d_in[6];
    const float* spa_pj   = (const float*)d_in[7];
    const float* tmp_pj   = (const float*)d_in[8];
    const float* theta_w  = (const float*)d_in[9];
    const float* theta_b  = (const float*)d_in[10];
    float* out = (float*)d_out;

    char* p = (char*)d_ws;
    auto alloc = [&](size_t bytes) -> void* {
        void* r = (void*)p;
        p += (bytes + 255) & ~(size_t)255;
        return r;
    };
    __bf16* Mt      = (__bf16*)alloc((size_t)NN * NN * 2);
    __bf16* Ms      = (__bf16*)alloc((size_t)NN * NN * 2);
    __bf16* cur_bf  = (__bf16*)alloc((size_t)NN * DD * 2);
    __bf16* curT    = (__bf16*)alloc((size_t)NN * DD * 2);
    __bf16* preT    = (__bf16*)alloc((size_t)NN * DD * 2);
    __bf16* pTs     = (__bf16*)alloc((size_t)DD * DD * 2);
    __bf16* pTt     = (__bf16*)alloc((size_t)DD * DD * 2);
    __bf16* pTn     = (__bf16*)alloc((size_t)DD * DD * 2);
    __bf16* pTspa   = (__bf16*)alloc((size_t)DD * DD * 2);
    __bf16* pTtmp   = (__bf16*)alloc((size_t)DD * DD * 2);
    __bf16* thetaBf = (__bf16*)alloc((size_t)DD * DD * 2);
    float* negMs    = (float*)alloc((size_t)NN * DD * 4);
    float* negMt    = (float*)alloc((size_t)NN * DD * 4);
    float* nodeFea  = (float*)alloc((size_t)NN * DD * 4);
    float* feaS     = (float*)alloc((size_t)NN * DD * 4);
    float* feaT     = (float*)alloc((size_t)NN * DD * 4);
    float* spaF     = (float*)alloc((size_t)NN * DD * 4);
    float* tmpF     = (float*)alloc((size_t)NN * DD * 4);
    float* rsS      = (float*)alloc((size_t)NN * 4);
    float* rsT      = (float*)alloc((size_t)NN * 4);
    float* spaA     = (float*)alloc((size_t)NN * 4);
    float* tmpA     = (float*)alloc((size_t)NN * 4);
    float* pAbsT    = (float*)alloc((size_t)NN * 4);
    float* pSqT     = (float*)alloc((size_t)NN * 4);
    float* pAbsS    = (float*)alloc((size_t)NN * 4);
    float* pSqS     = (float*)alloc((size_t)NN * 4);
    float* pDiff    = (float*)alloc(512 * 4);

    k_prep<<<dim3(NN / 64, DD / 64, 2), 256, 0, stream>>>(cur, pre, cur_bf, curT, preT);
    k_proj<<<dim3(DD, 6), 256, 0, stream>>>(r_proj_s, r_proj_t, node_pj, spa_pj, tmp_pj, theta_w,
                                            pTs, pTt, pTn, pTspa, pTtmp, thetaBf);
    k_conv_t<<<NN, 256, 0, stream>>>(inc_t, Mt, rsT, pAbsT, pSqT);
    k_conv_s<<<NN, 256, 0, stream>>>(inc_s, Ms, rsS, pAbsS, pSqS);
    k_small3<<<dim3(4, 64, 3), 256, 0, stream>>>(cur_bf, pTs, pTt, pTn, negMs, negMt, nodeFea);
    k_big<<<dim3(4, 64, 2), 256, 0, stream>>>(Mt, Ms, preT, curT, negMt, negMs, cur, feaT, feaS, pDiff);
    k_fea<<<dim3(4, 64, 2), 256, 0, stream>>>(feaS, feaT, rsS, rsT, pTspa, pTtmp, spaF, tmpF);
    k_attn<<<NN / 4, 256, 0, stream>>>(spaF, tmpF, nodeFea, spaA, tmpA);
    k_final<<<dim3(4, 64), 256, 0, stream>>>(spaF, tmpF, spaA, tmpA, thetaBf, theta_b, out);
    k_loss<<<1, 256, 0, stream>>>(pAbsT, pSqT, pAbsS, pSqS, pDiff, out);
}